// Round 4
// baseline (448.172 us; speedup 1.0000x reference)
//
#include <hip/hip_runtime.h>
#include <cstdint>

#define MUL0 16
#define MUL1 8
#define NRBF 8
#define HID 64
#define WNUM 576
#define CUTOFF 5.0f
#define EPSF 1e-8f

#define INV_SQRT3 0.57735026918962576f
#define A_PATH    0.20412414523193154f   /* 1/sqrt(24) */
#define Q16       0.25f                  /* 1/sqrt(16) */
#define Q8        0.35355339059327373f   /* 1/sqrt(8)  */
#define PI_OVER_CUT 0.62831853071795865f /* pi/5 */

typedef _Float16 f16;
typedef _Float16 f16x8 __attribute__((ext_vector_type(8)));
typedef float f32x4 __attribute__((ext_vector_type(4)));

__device__ __forceinline__ float sigm(float x) { return 1.0f / (1.0f + __expf(-x)); }

// ---------------- prep: w_r2 (64 x 576 f32) -> W2T (576 x 64 f16) ----------------
extern "C" __global__ __launch_bounds__(256) void k_prep_w2t(
    const float* __restrict__ w_r2, f16* __restrict__ W2T) {
  int t = blockIdx.x * 256 + threadIdx.x;
  if (t >= HID * WNUM) return;
  int n = t >> 6, k = t & 63;
  W2T[n * 64 + k] = (f16)w_r2[k * WNUM + n];
}

// ---------------- node irrep norm (vectorized, 64-thread blocks) ----------------
extern "C" __global__ __launch_bounds__(64) void k_xnorm(
    const float* __restrict__ x, float* __restrict__ xnorm, int N) {
  int n = blockIdx.x * 64 + threadIdx.x;
  if (n >= N) return;
  const float4* xr = (const float4*)(x + (long long)n * 40);
  float4 vv[10];
#pragma unroll
  for (int i = 0; i < 10; i++) vv[i] = xr[i];
  float* f = (float*)vv;
  float ss = 0.f, vs = 0.f;
#pragma unroll
  for (int i = 0; i < 16; i++) ss += f[i] * f[i];
#pragma unroll
  for (int i = 16; i < 40; i++) vs += f[i] * f[i];
  float sr = rsqrtf(ss * (1.0f / 16.0f) + EPSF);
  float vr = rsqrtf(vs * (1.0f / 8.0f) + EPSF);
#pragma unroll
  for (int i = 0; i < 16; i++) f[i] *= sr;
#pragma unroll
  for (int i = 16; i < 40; i++) f[i] *= vr;
  float4* o = (float4*)(xnorm + (long long)n * 40);
#pragma unroll
  for (int i = 0; i < 10; i++) o[i] = vv[i];
}

// ---------------- counting sort by dst: hist -> scan -> scatter ----------------
extern "C" __global__ __launch_bounds__(256) void k_hist(
    const int* __restrict__ edst, int* __restrict__ hist, int E) {
  int e = blockIdx.x * 256 + threadIdx.x;
  if (e < E) atomicAdd(&hist[edst[e]], 1);
}

extern "C" __global__ __launch_bounds__(256) void k_scan1(
    const int* __restrict__ hist, int* __restrict__ iscan,
    int* __restrict__ bsum, int N) {
  __shared__ int sm[256];
  int i = blockIdx.x * 256 + threadIdx.x;
  int t = threadIdx.x;
  sm[t] = (i < N) ? hist[i] : 0;
  __syncthreads();
#pragma unroll
  for (int d = 1; d < 256; d <<= 1) {
    int add = (t >= d) ? sm[t - d] : 0;
    __syncthreads();
    sm[t] += add;
    __syncthreads();
  }
  if (i < N) iscan[i] = sm[t];
  if (t == 255) bsum[blockIdx.x] = sm[255];
}

extern "C" __global__ __launch_bounds__(256) void k_scan2(
    int* __restrict__ bsum, int nb) {
  __shared__ int sm[256];
  int t = threadIdx.x;
  sm[t] = (t < nb) ? bsum[t] : 0;
  __syncthreads();
#pragma unroll
  for (int d = 1; d < 256; d <<= 1) {
    int add = (t >= d) ? sm[t - d] : 0;
    __syncthreads();
    sm[t] += add;
    __syncthreads();
  }
  if (t < nb) bsum[t] = sm[t];  // inclusive sums of block totals
}

extern "C" __global__ __launch_bounds__(256) void k_scan3(
    const int* __restrict__ hist, const int* __restrict__ iscan,
    const int* __restrict__ bsum, int* __restrict__ cursor, int N) {
  int i = blockIdx.x * 256 + threadIdx.x;
  if (i >= N) return;
  int base = blockIdx.x ? bsum[blockIdx.x - 1] : 0;
  cursor[i] = iscan[i] - hist[i] + base;  // global exclusive prefix
}

extern "C" __global__ __launch_bounds__(256) void k_scatter(
    const int* __restrict__ esrc, const int* __restrict__ edst,
    const float* __restrict__ sh, const float* __restrict__ rbf,
    const float* __restrict__ elen, int* __restrict__ cursor,
    int* __restrict__ esrc_s, int* __restrict__ edst_s,
    float* __restrict__ sh_s, float* __restrict__ rbf_s,
    float* __restrict__ elen_s, int E) {
  int e = blockIdx.x * 256 + threadIdx.x;
  if (e >= E) return;
  int d = edst[e];
  int p = atomicAdd(&cursor[d], 1);
  esrc_s[p] = esrc[e];
  edst_s[p] = d;
  elen_s[p] = elen[e];
  *(float4*)&sh_s[(long long)p * 4] = *(const float4*)&sh[(long long)e * 4];
  *(float4*)&rbf_s[(long long)p * 8] = *(const float4*)&rbf[(long long)e * 8];
  *(float4*)&rbf_s[(long long)p * 8 + 4] = *(const float4*)&rbf[(long long)e * 8 + 4];
}

// ---------------- fused edge kernel (dst-sorted edges) ----------------
// block = 256 threads = 4 waves; each wave owns 16 consecutive sorted edges.
// Block-wide barriers keep W2T sweep + atomic bursts time-aligned (R1: removing
// them blew FETCH up 13x). launch_bounds(256,5): R2's 168 VGPR -> 11.6% occ.
// Epilogue run-compresses atomics over sorted dst (R3: atomic queue was the
// shared-server bottleneck: occ 11.6->52% gave only 1.46x).
extern "C" __global__ __launch_bounds__(256, 5) void k_edge(
    const float* __restrict__ xnorm, const int* __restrict__ esrc,
    const int* __restrict__ edst, const float* __restrict__ sh,
    const float* __restrict__ rbf, const float* __restrict__ elen,
    const float* __restrict__ w_r1, const float* __restrict__ b_r1,
    const float* __restrict__ w_g1, const float* __restrict__ b_g1,
    const float* __restrict__ w_g2, const float* __restrict__ b_g2,
    const float* __restrict__ b_r2, const f16* __restrict__ W2T,
    float* __restrict__ agg0, float* __restrict__ agg1,
    float* __restrict__ normb, int E) {
  // strides padded so quad-spaced rows land on distinct banks (R1-verified:
  // SQ_LDS_BANK_CONFLICT 1.1e7 -> 4e5)
  __shared__ __align__(16) f16   s_H[4][16][72];
  __shared__ __align__(16) float s_sn[4][16][20];
  __shared__ __align__(16) float s_v[4][16][28];
  __shared__ __align__(16) float s_a1[4][16][12];
  __shared__ __align__(16) float s_sh[4][16][4];
  __shared__ __align__(16) float s_rbf[4][16][8];
  __shared__ float s_ew[4][16];
  __shared__ int   s_dst[4][16];

  const int t = threadIdx.x;
  const int w = t >> 6;
  const int lane = t & 63;
  const long long eb = (long long)blockIdx.x * 64 + w * 16;  // wave's first edge

  // ---- A0: staging (sorted arrays, coalesced) ----
  const int ge_l = lane >> 2;
  const int part = lane & 3;
  const long long ge = eb + ge_l;
  int srcn = 0;
  float4 shv = {0.f, 0.f, 0.f, 0.f};
  if (ge < E) {
    srcn = esrc[ge];
    shv = *(const float4*)&sh[ge * 4];
  }
  {
    long long gb = eb * 8 + lane;
    float r0 = (gb < (long long)E * 8) ? rbf[gb] : 0.f;
    float r1 = (gb + 64 < (long long)E * 8) ? rbf[gb + 64] : 0.f;
    (&s_rbf[w][0][0])[lane] = r0;
    (&s_rbf[w][0][0])[lane + 64] = r1;
    long long gs = eb * 4 + lane;
    (&s_sh[w][0][0])[lane] = (gs < (long long)E * 4) ? sh[gs] : 0.f;
    if (lane < 16) {
      long long g2 = eb + lane;
      s_dst[w][lane] = (g2 < E) ? edst[g2] : 0;
    }
  }
  __syncthreads();

  // ---- A1: gather + transform (4 lanes per edge, float4 loads) ----
  {
    const float* xr = xnorm + (long long)srcn * 40;
    if (part < 2) {
      float4 aLo = *(const float4*)(xr + part * 8);
      float4 aHi = *(const float4*)(xr + part * 8 + 4);
      *(float4*)&s_sn[w][ge_l][part * 8] = aLo;
      *(float4*)&s_sn[w][ge_l][part * 8 + 4] = aHi;
    } else {
      const int i0 = (part - 2) * 4;
      const float* vp = xr + 16 + i0 * 3;
      float4 v0 = *(const float4*)(vp);
      float4 v1 = *(const float4*)(vp + 4);
      float4 v2 = *(const float4*)(vp + 8);
      *(float4*)&s_v[w][ge_l][i0 * 3] = v0;
      *(float4*)&s_v[w][ge_l][i0 * 3 + 4] = v1;
      *(float4*)&s_v[w][ge_l][i0 * 3 + 8] = v2;
      float s1x = shv.y, s1y = shv.z, s1z = shv.w;
      s_a1[w][ge_l][i0]     = INV_SQRT3 * (v0.x * s1x + v0.y * s1y + v0.z * s1z);
      s_a1[w][ge_l][i0 + 1] = INV_SQRT3 * (v0.w * s1x + v1.x * s1y + v1.y * s1z);
      s_a1[w][ge_l][i0 + 2] = INV_SQRT3 * (v1.z * s1x + v1.w * s1y + v2.x * s1z);
      s_a1[w][ge_l][i0 + 3] = INV_SQRT3 * (v2.y * s1x + v2.z * s1y + v2.w * s1z);
    }
  }

  // ---- A2: hidden layer H (f16), lane = h, 16 edges of this wave ----
  {
    float wr[8];
#pragma unroll
    for (int r = 0; r < 8; r++) wr[r] = w_r1[r * HID + lane];
    float bh = b_r1[lane];
#pragma unroll
    for (int u = 0; u < 16; u++) {
      float4 ra = *(const float4*)&s_rbf[w][u][0];
      float4 rb = *(const float4*)&s_rbf[w][u][4];
      float acc = bh + ra.x * wr[0] + ra.y * wr[1] + ra.z * wr[2] + ra.w * wr[3]
                     + rb.x * wr[4] + rb.y * wr[5] + rb.z * wr[6] + rb.w * wr[7];
      s_H[w][u][lane] = (f16)(acc * sigm(acc));
    }
  }

  // ---- A3: gate MLP, all 64 lanes (16 h-units per lane) + shfl reduce ----
  {
    const int eg = lane & 15;
    const int grp = lane >> 4;
    float4 ga = *(const float4*)&s_rbf[w][eg][0];
    float4 gb = *(const float4*)&s_rbf[w][eg][4];
    float rv[8] = {ga.x, ga.y, ga.z, ga.w, gb.x, gb.y, gb.z, gb.w};
    float tt[16];
    {
      const float4 b0 = *(const float4*)&b_g1[grp * 16];
      const float4 b1 = *(const float4*)&b_g1[grp * 16 + 4];
      const float4 b2 = *(const float4*)&b_g1[grp * 16 + 8];
      const float4 b3 = *(const float4*)&b_g1[grp * 16 + 12];
      tt[0] = b0.x; tt[1] = b0.y; tt[2] = b0.z; tt[3] = b0.w;
      tt[4] = b1.x; tt[5] = b1.y; tt[6] = b1.z; tt[7] = b1.w;
      tt[8] = b2.x; tt[9] = b2.y; tt[10] = b2.z; tt[11] = b2.w;
      tt[12] = b3.x; tt[13] = b3.y; tt[14] = b3.z; tt[15] = b3.w;
    }
#pragma unroll
    for (int r = 0; r < 8; r++) {
      const float* wg = w_g1 + r * HID + grp * 16;
      float4 w0 = *(const float4*)(wg);
      float4 w1 = *(const float4*)(wg + 4);
      float4 w2 = *(const float4*)(wg + 8);
      float4 w3 = *(const float4*)(wg + 12);
      float rr = rv[r];
      tt[0] += rr * w0.x; tt[1] += rr * w0.y; tt[2] += rr * w0.z; tt[3] += rr * w0.w;
      tt[4] += rr * w1.x; tt[5] += rr * w1.y; tt[6] += rr * w1.z; tt[7] += rr * w1.w;
      tt[8] += rr * w2.x; tt[9] += rr * w2.y; tt[10] += rr * w2.z; tt[11] += rr * w2.w;
      tt[12] += rr * w3.x; tt[13] += rr * w3.y; tt[14] += rr * w3.z; tt[15] += rr * w3.w;
    }
    float gw[16];
    {
      const float4 g0 = *(const float4*)&w_g2[grp * 16];
      const float4 g1 = *(const float4*)&w_g2[grp * 16 + 4];
      const float4 g2 = *(const float4*)&w_g2[grp * 16 + 8];
      const float4 g3 = *(const float4*)&w_g2[grp * 16 + 12];
      gw[0] = g0.x; gw[1] = g0.y; gw[2] = g0.z; gw[3] = g0.w;
      gw[4] = g1.x; gw[5] = g1.y; gw[6] = g1.z; gw[7] = g1.w;
      gw[8] = g2.x; gw[9] = g2.y; gw[10] = g2.z; gw[11] = g2.w;
      gw[12] = g3.x; gw[13] = g3.y; gw[14] = g3.z; gw[15] = g3.w;
    }
    float accp = 0.f;
#pragma unroll
    for (int k = 0; k < 16; k++) accp += tt[k] * sigm(tt[k]) * gw[k];
    accp += __shfl_xor(accp, 16);
    accp += __shfl_xor(accp, 32);
    if (lane < 16) {
      long long g2e = eb + lane;
      float ew = 0.f;
      if (g2e < E) {
        float len = elen[g2e];
        float cw = (len < CUTOFF) ? 0.5f * (__cosf(PI_OVER_CUT * len) + 1.0f) : 0.f;
        ew = cw * sigm(accp + b_g2[0]);
      }
      s_ew[w][lane] = ew;
    }
  }
  __syncthreads();

  // ---- B: MFMA over 36 j-tiles, four branch-free class loops ----
  const int quad = lane >> 4;
  const int c = lane & 15;

  const f16x8 af0 = *(const f16x8*)&s_H[w][c][quad * 8];
  const f16x8 af1 = *(const f16x8*)&s_H[w][c][32 + quad * 8];

  float p1[4] = {0.f, 0.f, 0.f, 0.f};
  float p2[4] = {0.f, 0.f, 0.f, 0.f};
  float t3[4] = {0.f, 0.f, 0.f, 0.f};
  float mx[4] = {0.f, 0.f, 0.f, 0.f};
  float my[4] = {0.f, 0.f, 0.f, 0.f};
  float mz[4] = {0.f, 0.f, 0.f, 0.f};

  const f16* wb = W2T + (long long)c * 64 + quad * 8;
  const float* bp = b_r2 + c;

#pragma unroll 2
  for (int jt = 0; jt < 16; jt++) {
    f16x8 b0 = *(const f16x8*)(wb + jt * 1024);
    f16x8 b1 = *(const f16x8*)(wb + jt * 1024 + 32);
    float bias = bp[jt * 16];
    f32x4 C = {0.f, 0.f, 0.f, 0.f};
    C = __builtin_amdgcn_mfma_f32_16x16x32_f16(af0, b0, C, 0, 0, 0);
    C = __builtin_amdgcn_mfma_f32_16x16x32_f16(af1, b1, C, 0, 0, 0);
#pragma unroll
    for (int r = 0; r < 4; r++)
      p1[r] += s_sn[w][quad * 4 + r][jt] * (C[r] + bias);
  }
#pragma unroll 2
  for (int jt = 16; jt < 24; jt++) {
    f16x8 b0 = *(const f16x8*)(wb + jt * 1024);
    f16x8 b1 = *(const f16x8*)(wb + jt * 1024 + 32);
    float bias = bp[jt * 16];
    f32x4 C = {0.f, 0.f, 0.f, 0.f};
    C = __builtin_amdgcn_mfma_f32_16x16x32_f16(af0, b0, C, 0, 0, 0);
    C = __builtin_amdgcn_mfma_f32_16x16x32_f16(af1, b1, C, 0, 0, 0);
    const int i = jt - 16;
#pragma unroll
    for (int r = 0; r < 4; r++)
      p2[r] += s_a1[w][quad * 4 + r][i] * (C[r] + bias);
  }
#pragma unroll 2
  for (int jt = 24; jt < 32; jt++) {
    f16x8 b0 = *(const f16x8*)(wb + jt * 1024);
    f16x8 b1 = *(const f16x8*)(wb + jt * 1024 + 32);
    float bias = bp[jt * 16];
    f32x4 C = {0.f, 0.f, 0.f, 0.f};
    C = __builtin_amdgcn_mfma_f32_16x16x32_f16(af0, b0, C, 0, 0, 0);
    C = __builtin_amdgcn_mfma_f32_16x16x32_f16(af1, b1, C, 0, 0, 0);
    const int i = (jt - 24) * 2 + (c >> 3);
#pragma unroll
    for (int r = 0; r < 4; r++)
      t3[r] += s_sn[w][quad * 4 + r][i] * (C[r] + bias);
  }
#pragma unroll 2
  for (int jt = 32; jt < 36; jt++) {
    f16x8 b0 = *(const f16x8*)(wb + jt * 1024);
    f16x8 b1 = *(const f16x8*)(wb + jt * 1024 + 32);
    float bias = bp[jt * 16];
    f32x4 C = {0.f, 0.f, 0.f, 0.f};
    C = __builtin_amdgcn_mfma_f32_16x16x32_f16(af0, b0, C, 0, 0, 0);
    C = __builtin_amdgcn_mfma_f32_16x16x32_f16(af1, b1, C, 0, 0, 0);
    const int i = (jt - 32) * 2 + (c >> 3);
#pragma unroll
    for (int r = 0; r < 4; r++) {
      float wvv = C[r] + bias;
      mx[r] += s_v[w][quad * 4 + r][3 * i] * wvv;
      my[r] += s_v[w][quad * 4 + r][3 * i + 1] * wvv;
      mz[r] += s_v[w][quad * 4 + r][3 * i + 2] * wvv;
    }
  }

  // fold the two column-halves (c and c^8 share output j = c&7)
#pragma unroll
  for (int r = 0; r < 4; r++) {
    t3[r] += __shfl_xor(t3[r], 8);
    mx[r] += __shfl_xor(mx[r], 8);
    my[r] += __shfl_xor(my[r], 8);
    mz[r] += __shfl_xor(mz[r], 8);
  }

  // ---- epilogue: run-compressed atomic scatter over sorted dst ----
  {
    int cur = s_dst[w][quad * 4];
    float acc0 = 0.f, a1x = 0.f, a1y = 0.f, a1z = 0.f, nacc = 0.f;
#pragma unroll
    for (int r = 0; r < 4; r++) {
      const int e = quad * 4 + r;
      const int dst = s_dst[w][e];
      if (dst != cur) {
        atomicAdd(&agg0[(long long)cur * 16 + c], acc0);
        if (c < 8) {
          long long b = (long long)cur * 24 + (long long)c * 3;
          atomicAdd(&agg1[b], a1x);
          atomicAdd(&agg1[b + 1], a1y);
          atomicAdd(&agg1[b + 2], a1z);
        } else if (c == 8) {
          atomicAdd(&normb[cur], nacc);
        }
        acc0 = a1x = a1y = a1z = nacc = 0.f;
        cur = dst;
      }
      float ew = s_ew[w][e];
      float sc = A_PATH * ew;
      float sh0 = s_sh[w][e][0];
      acc0 += (sh0 * p1[r] + p2[r]) * sc;
      if (c < 8) {
        float t3v = t3[r] * sc;
        float scs = sc * sh0;
        a1x += t3v * s_sh[w][e][1] + mx[r] * scs;
        a1y += t3v * s_sh[w][e][2] + my[r] * scs;
        a1z += t3v * s_sh[w][e][3] + mz[r] * scs;
      } else if (c == 8) {
        nacc += ew;
      }
    }
    atomicAdd(&agg0[(long long)cur * 16 + c], acc0);
    if (c < 8) {
      long long b = (long long)cur * 24 + (long long)c * 3;
      atomicAdd(&agg1[b], a1x);
      atomicAdd(&agg1[b + 1], a1y);
      atomicAdd(&agg1[b + 2], a1z);
    } else if (c == 8) {
      atomicAdd(&normb[cur], nacc);
    }
  }
}

// ---------------- final node kernel (64-thread blocks, vectorized) ----------------
extern "C" __global__ __launch_bounds__(64) void k_node(
    const float* __restrict__ x, const float* __restrict__ xnorm,
    const float* __restrict__ agg0, const float* __restrict__ agg1,
    const float* __restrict__ normb, const float* __restrict__ Wm_s,
    const float* __restrict__ Wm_v, const float* __restrict__ Wu_s,
    const float* __restrict__ Wu_v, const float* __restrict__ Ws_s,
    const float* __restrict__ Ws_v, const float* __restrict__ res_scale_p,
    float* __restrict__ out, int N) {
  __shared__ float sWms[384];
  __shared__ float sWmv[64];
  __shared__ float sWus[256];
  __shared__ float sWuv[64];
  __shared__ float sWss[256];
  __shared__ float sWsv[64];
  int t = threadIdx.x;
  for (int i = t; i < 384; i += 64) sWms[i] = Wm_s[i];
  sWmv[t] = Wm_v[t];
  for (int i = t; i < 256; i += 64) sWus[i] = Wu_s[i];
  sWuv[t] = Wu_v[t];
  for (int i = t; i < 256; i += 64) sWss[i] = Ws_s[i];
  sWsv[t] = Ws_v[t];
  __syncthreads();
  int n = blockIdx.x * 64 + t;
  if (n >= N) return;

  float inv = 1.0f / fmaxf(normb[n], EPSF);
  float4 a04[4], a14[6];
  {
    const float4* p = (const float4*)(agg0 + (long long)n * 16);
#pragma unroll
    for (int i = 0; i < 4; i++) a04[i] = p[i];
    const float4* q = (const float4*)(agg1 + (long long)n * 24);
#pragma unroll
    for (int i = 0; i < 6; i++) a14[i] = q[i];
  }
  float* a0 = (float*)a04;
  float* a1 = (float*)a14;
#pragma unroll
  for (int i = 0; i < 16; i++) a0[i] *= inv;
#pragma unroll
  for (int i = 0; i < 24; i++) a1[i] *= inv;

  float scal[16], gate[8];
#pragma unroll
  for (int jj = 0; jj < 24; jj++) {
    float acc = 0.f;
#pragma unroll
    for (int i = 0; i < 16; i++) acc += a0[i] * sWms[i * 24 + jj];
    acc *= Q16;
    if (jj < 16) scal[jj] = acc * sigm(acc);
    else gate[jj - 16] = sigm(acc);
  }
  float vg[24];
#pragma unroll
  for (int j = 0; j < 8; j++) {
    float g = gate[j];
#pragma unroll
    for (int cc = 0; cc < 3; cc++) {
      float acc = 0.f;
#pragma unroll
      for (int i = 0; i < 8; i++) acc += a1[i * 3 + cc] * sWmv[i * 8 + j];
      vg[j * 3 + cc] = acc * Q8 * g;
    }
  }
  float4 xn4[10], xo4[10];
  {
    const float4* p = (const float4*)(xnorm + (long long)n * 40);
    const float4* q = (const float4*)(x + (long long)n * 40);
#pragma unroll
    for (int i = 0; i < 10; i++) { xn4[i] = p[i]; xo4[i] = q[i]; }
  }
  const float* xn = (const float*)xn4;
  const float* xo = (const float*)xo4;
  float rs = res_scale_p[0];

  float4 ob[10];
  float* ov = (float*)ob;
#pragma unroll
  for (int j = 0; j < 16; j++) {
    float acc = 0.f, acc2 = 0.f;
#pragma unroll
    for (int i = 0; i < 16; i++) {
      acc += scal[i] * sWus[i * 16 + j];
      acc2 += xn[i] * sWss[i * 16 + j];
    }
    ov[j] = xo[j] + rs * ((acc + acc2) * Q16);
  }
#pragma unroll
  for (int j = 0; j < 8; j++) {
#pragma unroll
    for (int cc = 0; cc < 3; cc++) {
      float acc = 0.f;
#pragma unroll
      for (int i = 0; i < 8; i++)
        acc += vg[i * 3 + cc] * sWuv[i * 8 + j] + xn[16 + i * 3 + cc] * sWsv[i * 8 + j];
      ov[16 + j * 3 + cc] = xo[16 + j * 3 + cc] + rs * (acc * Q8);
    }
  }
  float4* po = (float4*)(out + (long long)n * 40);
#pragma unroll
  for (int i = 0; i < 10; i++) po[i] = ob[i];
}

// ---------------- launch ----------------
extern "C" void kernel_launch(void* const* d_in, const int* in_sizes, int n_in,
                              void* d_out, int out_size, void* d_ws, size_t ws_size,
                              hipStream_t stream) {
  const float* x = (const float*)d_in[0];
  const int* esrc = (const int*)d_in[1];
  const int* edst = (const int*)d_in[2];
  const float* sh = (const float*)d_in[3];
  const float* rbf = (const float*)d_in[4];
  const float* elen = (const float*)d_in[5];
  const float* w_r1 = (const float*)d_in[6];
  const float* b_r1 = (const float*)d_in[7];
  const float* w_r2 = (const float*)d_in[8];
  const float* b_r2 = (const float*)d_in[9];
  const float* w_g1 = (const float*)d_in[10];
  const float* b_g1 = (const float*)d_in[11];
  const float* w_g2 = (const float*)d_in[12];
  const float* b_g2 = (const float*)d_in[13];
  const float* Wm_s = (const float*)d_in[14];
  const float* Wm_v = (const float*)d_in[15];
  const float* Wu_s = (const float*)d_in[16];
  const float* Wu_v = (const float*)d_in[17];
  const float* Ws_s = (const float*)d_in[18];
  const float* Ws_v = (const float*)d_in[19];
  const float* res_scale = (const float*)d_in[20];

  const int N = in_sizes[0] / 40;
  const int E = in_sizes[1];

  char* ws = (char*)d_ws;
  size_t off = 0;
  float* xnorm = (float*)(ws + off); off += (size_t)N * 40 * sizeof(float);
  off = (off + 255) & ~(size_t)255;
  float* agg0 = (float*)(ws + off); off += (size_t)N * 16 * sizeof(float);
  float* agg1 = (float*)(ws + off); off += (size_t)N * 24 * sizeof(float);
  float* normb = (float*)(ws + off); off += (size_t)N * sizeof(float);
  off = (off + 255) & ~(size_t)255;
  f16* W2T = (f16*)(ws + off); off += (size_t)WNUM * 64 * sizeof(f16);
  off = (off + 255) & ~(size_t)255;
  int* hist   = (int*)(ws + off); off += (size_t)N * sizeof(int);
  int* iscan  = (int*)(ws + off); off += (size_t)N * sizeof(int);
  int* cursor = (int*)(ws + off); off += (size_t)N * sizeof(int);
  int* bsum   = (int*)(ws + off); off += 256 * sizeof(int);
  off = (off + 255) & ~(size_t)255;
  int* esrc_s = (int*)(ws + off); off += (size_t)E * sizeof(int);
  int* edst_s = (int*)(ws + off); off += (size_t)E * sizeof(int);
  float* elen_s = (float*)(ws + off); off += (size_t)E * sizeof(float);
  off = (off + 255) & ~(size_t)255;
  float* sh_s  = (float*)(ws + off); off += (size_t)E * 4 * sizeof(float);
  float* rbf_s = (float*)(ws + off); off += (size_t)E * 8 * sizeof(float);

  // zero accumulators (agg0, agg1, normb contiguous) and histogram
  hipMemsetAsync(agg0, 0, (size_t)N * 41 * sizeof(float), stream);
  hipMemsetAsync(hist, 0, (size_t)N * sizeof(int), stream);

  const int nbE = (E + 255) / 256;
  const int nbN = (N + 255) / 256;

  k_hist<<<nbE, 256, 0, stream>>>(edst, hist, E);
  k_scan1<<<nbN, 256, 0, stream>>>(hist, iscan, bsum, N);
  k_scan2<<<1, 256, 0, stream>>>(bsum, nbN);
  k_scan3<<<nbN, 256, 0, stream>>>(hist, iscan, bsum, cursor, N);
  k_scatter<<<nbE, 256, 0, stream>>>(esrc, edst, sh, rbf, elen, cursor,
                                     esrc_s, edst_s, sh_s, rbf_s, elen_s, E);

  k_prep_w2t<<<(HID * WNUM + 255) / 256, 256, 0, stream>>>(w_r2, W2T);
  k_xnorm<<<(N + 63) / 64, 64, 0, stream>>>(x, xnorm, N);

  int nblk = (E + 63) / 64;
  k_edge<<<nblk, 256, 0, stream>>>(xnorm, esrc_s, edst_s, sh_s, rbf_s, elen_s,
                                   w_r1, b_r1, w_g1, b_g1, w_g2, b_g2, b_r2,
                                   W2T, agg0, agg1, normb, E);

  k_node<<<(N + 63) / 64, 64, 0, stream>>>(x, xnorm, agg0, agg1, normb, Wm_s,
                                           Wm_v, Wu_s, Wu_v, Ws_s, Ws_v,
                                           res_scale, (float*)d_out, N);
}

// Round 5
// 370.165 us; speedup vs baseline: 1.2107x; 1.2107x over previous
//
#include <hip/hip_runtime.h>
#include <cstdint>

#define MUL0 16
#define MUL1 8
#define NRBF 8
#define HID 64
#define WNUM 576
#define CUTOFF 5.0f
#define EPSF 1e-8f

#define INV_SQRT3 0.57735026918962576f
#define A_PATH    0.20412414523193154f   /* 1/sqrt(24) */
#define Q16       0.25f                  /* 1/sqrt(16) */
#define Q8        0.35355339059327373f   /* 1/sqrt(8)  */
#define PI_OVER_CUT 0.62831853071795865f /* pi/5 */

typedef _Float16 f16;
typedef _Float16 f16x8 __attribute__((ext_vector_type(8)));
typedef float f32x4 __attribute__((ext_vector_type(4)));

__device__ __forceinline__ float sigm(float x) { return 1.0f / (1.0f + __expf(-x)); }

// ---------------- prep: w_r2 (64 x 576 f32) -> W2T (576 x 64 f16) ----------------
extern "C" __global__ __launch_bounds__(256) void k_prep_w2t(
    const float* __restrict__ w_r2, f16* __restrict__ W2T) {
  int t = blockIdx.x * 256 + threadIdx.x;
  if (t >= HID * WNUM) return;
  int n = t >> 6, k = t & 63;
  W2T[n * 64 + k] = (f16)w_r2[k * WNUM + n];
}

// ---------------- node irrep norm ----------------
extern "C" __global__ __launch_bounds__(64) void k_xnorm(
    const float* __restrict__ x, float* __restrict__ xnorm, int N) {
  int n = blockIdx.x * 64 + threadIdx.x;
  if (n >= N) return;
  const float4* xr = (const float4*)(x + (long long)n * 40);
  float4 vv[10];
#pragma unroll
  for (int i = 0; i < 10; i++) vv[i] = xr[i];
  float* f = (float*)vv;
  float ss = 0.f, vs = 0.f;
#pragma unroll
  for (int i = 0; i < 16; i++) ss += f[i] * f[i];
#pragma unroll
  for (int i = 16; i < 40; i++) vs += f[i] * f[i];
  float sr = rsqrtf(ss * (1.0f / 16.0f) + EPSF);
  float vr = rsqrtf(vs * (1.0f / 8.0f) + EPSF);
#pragma unroll
  for (int i = 0; i < 16; i++) f[i] *= sr;
#pragma unroll
  for (int i = 16; i < 40; i++) f[i] *= vr;
  float4* o = (float4*)(xnorm + (long long)n * 40);
#pragma unroll
  for (int i = 0; i < 10; i++) o[i] = vv[i];
}

// ---------------- counting sort by dst: hist -> scan -> perm ----------------
extern "C" __global__ __launch_bounds__(256) void k_hist(
    const int* __restrict__ edst, int* __restrict__ hist, int E) {
  int e = blockIdx.x * 256 + threadIdx.x;
  if (e < E) atomicAdd(&hist[edst[e]], 1);
}

extern "C" __global__ __launch_bounds__(256) void k_scan1(
    const int* __restrict__ hist, int* __restrict__ iscan,
    int* __restrict__ bsum, int N) {
  __shared__ int sm[256];
  int i = blockIdx.x * 256 + threadIdx.x;
  int t = threadIdx.x;
  sm[t] = (i < N) ? hist[i] : 0;
  __syncthreads();
#pragma unroll
  for (int d = 1; d < 256; d <<= 1) {
    int add = (t >= d) ? sm[t - d] : 0;
    __syncthreads();
    sm[t] += add;
    __syncthreads();
  }
  if (i < N) iscan[i] = sm[t];
  if (t == 255) bsum[blockIdx.x] = sm[255];
}

extern "C" __global__ __launch_bounds__(256) void k_scan2(
    int* __restrict__ bsum, int nb) {
  __shared__ int sm[256];
  int t = threadIdx.x;
  sm[t] = (t < nb) ? bsum[t] : 0;
  __syncthreads();
#pragma unroll
  for (int d = 1; d < 256; d <<= 1) {
    int add = (t >= d) ? sm[t - d] : 0;
    __syncthreads();
    sm[t] += add;
    __syncthreads();
  }
  if (t < nb) bsum[t] = sm[t];
}

extern "C" __global__ __launch_bounds__(256) void k_scan3(
    const int* __restrict__ hist, const int* __restrict__ iscan,
    const int* __restrict__ bsum, int* __restrict__ cursor, int N) {
  int i = blockIdx.x * 256 + threadIdx.x;
  if (i >= N) return;
  int base = blockIdx.x ? bsum[blockIdx.x - 1] : 0;
  cursor[i] = iscan[i] - hist[i] + base;
}

// scatter ONLY a 4-byte permutation index (R4's 52 B/edge payload cost ~66 us)
extern "C" __global__ __launch_bounds__(256) void k_scatter(
    const int* __restrict__ edst, int* __restrict__ cursor,
    int* __restrict__ perm, int E) {
  int e = blockIdx.x * 256 + threadIdx.x;
  if (e >= E) return;
  int p = atomicAdd(&cursor[edst[e]], 1);
  perm[p] = e;
}

// ---------------- fused edge kernel: 32 edges/wave, perm-gathered ----------------
// 4 waves/block, 128 edges/block. Each b-tile of W2T now feeds 2 MFMA C-tiles
// (2.25 KB of weight stream per edge vs 4.5 in R4). LDS trimmed to 52 KB so
// 3 blocks/CU (12 waves) stay resident; launch_bounds(256,3) caps VGPR.
// Block-wide barriers kept (R1: removing them blew L2 FETCH up 13x).
extern "C" __global__ __launch_bounds__(256, 3) void k_edge(
    const float* __restrict__ xnorm, const int* __restrict__ perm,
    const int* __restrict__ esrc, const int* __restrict__ edst,
    const float* __restrict__ sh, const float* __restrict__ rbf,
    const float* __restrict__ elen,
    const float* __restrict__ w_r1, const float* __restrict__ b_r1,
    const float* __restrict__ w_g1, const float* __restrict__ b_g1,
    const float* __restrict__ w_g2, const float* __restrict__ b_g2,
    const float* __restrict__ b_r2, const f16* __restrict__ W2T,
    float* __restrict__ agg0, float* __restrict__ agg1,
    float* __restrict__ normb, int E) {
  __shared__ __align__(16) f16   s_H[4][32][72];    // 18432 B
  __shared__ __align__(16) float s_sn[4][32][20];   // 10240 B (2-way banks: free)
  __shared__ __align__(16) float s_v[4][32][24];    // 12288 B
  __shared__ __align__(16) float s_a1[4][32][12];   //  6144 B
  __shared__ __align__(16) float s_sh[4][32][4];    //  2048 B
  __shared__ __align__(16) float s_rbf[4][32][8];   //  4096 B  => 53248 total

  const int t = threadIdx.x;
  const int w = t >> 6;
  const int lane = t & 63;
  const long long eb = (long long)blockIdx.x * 128 + w * 32;  // wave's first edge

  // ---- A0: perm load + gathers (pl=0 fallback is safe: ew forced 0 later) ----
  int pl = 0, dstv = 0, srcv = 0;
  float lenv = 1e9f;
  if (lane < 32) {
    long long g2 = eb + lane;
    if (g2 < E) pl = perm[g2];
    srcv = esrc[pl];
    dstv = edst[pl];
    lenv = elen[pl];
    *(float4*)&s_sh[w][lane][0] = *(const float4*)&sh[(long long)pl * 4];
  }
  {
    int e = lane >> 1, half = lane & 1;
    int pe = __shfl(pl, e);
    *(float4*)&s_rbf[w][e][half * 4] =
        *(const float4*)&rbf[(long long)pe * 8 + half * 4];
  }
  __syncthreads();

  // ---- A1: gather xnorm + transform (4 lanes/edge, 2 groups) ----
  {
    const int ge_l = lane >> 2;
    const int part = lane & 3;
#pragma unroll
    for (int g = 0; g < 2; g++) {
      int e = g * 16 + ge_l;
      int srcn = __shfl(srcv, e);
      const float* xr = xnorm + (long long)srcn * 40;
      if (part < 2) {
        float4 aLo = *(const float4*)(xr + part * 8);
        float4 aHi = *(const float4*)(xr + part * 8 + 4);
        *(float4*)&s_sn[w][e][part * 8] = aLo;
        *(float4*)&s_sn[w][e][part * 8 + 4] = aHi;
      } else {
        const int i0 = (part - 2) * 4;
        const float* vp = xr + 16 + i0 * 3;
        float4 v0 = *(const float4*)(vp);
        float4 v1 = *(const float4*)(vp + 4);
        float4 v2 = *(const float4*)(vp + 8);
        *(float4*)&s_v[w][e][i0 * 3] = v0;
        *(float4*)&s_v[w][e][i0 * 3 + 4] = v1;
        *(float4*)&s_v[w][e][i0 * 3 + 8] = v2;
        float4 shq = *(const float4*)&s_sh[w][e][0];
        float s1x = shq.y, s1y = shq.z, s1z = shq.w;
        s_a1[w][e][i0]     = INV_SQRT3 * (v0.x * s1x + v0.y * s1y + v0.z * s1z);
        s_a1[w][e][i0 + 1] = INV_SQRT3 * (v0.w * s1x + v1.x * s1y + v1.y * s1z);
        s_a1[w][e][i0 + 2] = INV_SQRT3 * (v1.z * s1x + v1.w * s1y + v2.x * s1z);
        s_a1[w][e][i0 + 3] = INV_SQRT3 * (v2.y * s1x + v2.z * s1y + v2.w * s1z);
      }
    }
  }

  // ---- A2: hidden layer H (f16), lane = h, 32 edges ----
  {
    float wr[8];
#pragma unroll
    for (int r = 0; r < 8; r++) wr[r] = w_r1[r * HID + lane];
    float bh = b_r1[lane];
#pragma unroll 4
    for (int u = 0; u < 32; u++) {
      float4 ra = *(const float4*)&s_rbf[w][u][0];
      float4 rb = *(const float4*)&s_rbf[w][u][4];
      float acc = bh + ra.x * wr[0] + ra.y * wr[1] + ra.z * wr[2] + ra.w * wr[3]
                     + rb.x * wr[4] + rb.y * wr[5] + rb.z * wr[6] + rb.w * wr[7];
      s_H[w][u][lane] = (f16)(acc * sigm(acc));
    }
  }

  // ---- A3: gate MLP, 2 lanes/edge x 32 h-units, chunked ----
  float ewv = 0.f;
  {
    const int eg = lane & 31;
    const int hf = lane >> 5;
    float4 ga = *(const float4*)&s_rbf[w][eg][0];
    float4 gb = *(const float4*)&s_rbf[w][eg][4];
    float rv[8] = {ga.x, ga.y, ga.z, ga.w, gb.x, gb.y, gb.z, gb.w};
    float accp = 0.f;
#pragma unroll
    for (int ch = 0; ch < 2; ch++) {
      const int base = hf * 32 + ch * 16;
      float ttv[16];
      {
        const float4 b0 = *(const float4*)&b_g1[base];
        const float4 b1 = *(const float4*)&b_g1[base + 4];
        const float4 b2 = *(const float4*)&b_g1[base + 8];
        const float4 b3 = *(const float4*)&b_g1[base + 12];
        ttv[0] = b0.x; ttv[1] = b0.y; ttv[2] = b0.z; ttv[3] = b0.w;
        ttv[4] = b1.x; ttv[5] = b1.y; ttv[6] = b1.z; ttv[7] = b1.w;
        ttv[8] = b2.x; ttv[9] = b2.y; ttv[10] = b2.z; ttv[11] = b2.w;
        ttv[12] = b3.x; ttv[13] = b3.y; ttv[14] = b3.z; ttv[15] = b3.w;
      }
#pragma unroll
      for (int r = 0; r < 8; r++) {
        const float* wg = w_g1 + r * HID + base;
        float4 w0 = *(const float4*)(wg);
        float4 w1 = *(const float4*)(wg + 4);
        float4 w2 = *(const float4*)(wg + 8);
        float4 w3 = *(const float4*)(wg + 12);
        float rr = rv[r];
        ttv[0] += rr * w0.x; ttv[1] += rr * w0.y; ttv[2] += rr * w0.z; ttv[3] += rr * w0.w;
        ttv[4] += rr * w1.x; ttv[5] += rr * w1.y; ttv[6] += rr * w1.z; ttv[7] += rr * w1.w;
        ttv[8] += rr * w2.x; ttv[9] += rr * w2.y; ttv[10] += rr * w2.z; ttv[11] += rr * w2.w;
        ttv[12] += rr * w3.x; ttv[13] += rr * w3.y; ttv[14] += rr * w3.z; ttv[15] += rr * w3.w;
      }
      const float4 g0 = *(const float4*)&w_g2[base];
      const float4 g1 = *(const float4*)&w_g2[base + 4];
      const float4 g2 = *(const float4*)&w_g2[base + 8];
      const float4 g3 = *(const float4*)&w_g2[base + 12];
      float gw[16] = {g0.x, g0.y, g0.z, g0.w, g1.x, g1.y, g1.z, g1.w,
                      g2.x, g2.y, g2.z, g2.w, g3.x, g3.y, g3.z, g3.w};
#pragma unroll
      for (int k = 0; k < 16; k++) accp += ttv[k] * sigm(ttv[k]) * gw[k];
    }
    accp += __shfl_xor(accp, 32);
    if (lane < 32) {
      long long g2e = eb + lane;
      if (g2e < E) {
        float len = lenv;
        float cw = (len < CUTOFF) ? 0.5f * (__cosf(PI_OVER_CUT * len) + 1.0f) : 0.f;
        ewv = cw * sigm(accp + b_g2[0]);
      }
    }
  }
  __syncthreads();

  // ---- B: MFMA over 36 j-tiles x 2 edge-groups (b-tile reused) ----
  const int quad = lane >> 4;
  const int c = lane & 15;

  const f16x8 af00 = *(const f16x8*)&s_H[w][c][quad * 8];
  const f16x8 af01 = *(const f16x8*)&s_H[w][c][32 + quad * 8];
  const f16x8 af10 = *(const f16x8*)&s_H[w][16 + c][quad * 8];
  const f16x8 af11 = *(const f16x8*)&s_H[w][16 + c][32 + quad * 8];

  float p1[2][4] = {{0.f}}, p2[2][4] = {{0.f}}, t3[2][4] = {{0.f}};
  float mx[2][4] = {{0.f}}, my[2][4] = {{0.f}}, mz[2][4] = {{0.f}};

  const f16* wb = W2T + (long long)c * 64 + quad * 8;
  const float* bp = b_r2 + c;

#pragma unroll 2
  for (int jt = 0; jt < 16; jt++) {
    f16x8 b0 = *(const f16x8*)(wb + jt * 1024);
    f16x8 b1 = *(const f16x8*)(wb + jt * 1024 + 32);
    float bias = bp[jt * 16];
    f32x4 C0 = {0.f, 0.f, 0.f, 0.f};
    C0 = __builtin_amdgcn_mfma_f32_16x16x32_f16(af00, b0, C0, 0, 0, 0);
    C0 = __builtin_amdgcn_mfma_f32_16x16x32_f16(af01, b1, C0, 0, 0, 0);
    f32x4 C1 = {0.f, 0.f, 0.f, 0.f};
    C1 = __builtin_amdgcn_mfma_f32_16x16x32_f16(af10, b0, C1, 0, 0, 0);
    C1 = __builtin_amdgcn_mfma_f32_16x16x32_f16(af11, b1, C1, 0, 0, 0);
#pragma unroll
    for (int r = 0; r < 4; r++) {
      p1[0][r] += s_sn[w][quad * 4 + r][jt] * (C0[r] + bias);
      p1[1][r] += s_sn[w][16 + quad * 4 + r][jt] * (C1[r] + bias);
    }
  }
#pragma unroll 2
  for (int jt = 16; jt < 24; jt++) {
    f16x8 b0 = *(const f16x8*)(wb + jt * 1024);
    f16x8 b1 = *(const f16x8*)(wb + jt * 1024 + 32);
    float bias = bp[jt * 16];
    f32x4 C0 = {0.f, 0.f, 0.f, 0.f};
    C0 = __builtin_amdgcn_mfma_f32_16x16x32_f16(af00, b0, C0, 0, 0, 0);
    C0 = __builtin_amdgcn_mfma_f32_16x16x32_f16(af01, b1, C0, 0, 0, 0);
    f32x4 C1 = {0.f, 0.f, 0.f, 0.f};
    C1 = __builtin_amdgcn_mfma_f32_16x16x32_f16(af10, b0, C1, 0, 0, 0);
    C1 = __builtin_amdgcn_mfma_f32_16x16x32_f16(af11, b1, C1, 0, 0, 0);
    const int i = jt - 16;
#pragma unroll
    for (int r = 0; r < 4; r++) {
      p2[0][r] += s_a1[w][quad * 4 + r][i] * (C0[r] + bias);
      p2[1][r] += s_a1[w][16 + quad * 4 + r][i] * (C1[r] + bias);
    }
  }
#pragma unroll 2
  for (int jt = 24; jt < 32; jt++) {
    f16x8 b0 = *(const f16x8*)(wb + jt * 1024);
    f16x8 b1 = *(const f16x8*)(wb + jt * 1024 + 32);
    float bias = bp[jt * 16];
    f32x4 C0 = {0.f, 0.f, 0.f, 0.f};
    C0 = __builtin_amdgcn_mfma_f32_16x16x32_f16(af00, b0, C0, 0, 0, 0);
    C0 = __builtin_amdgcn_mfma_f32_16x16x32_f16(af01, b1, C0, 0, 0, 0);
    f32x4 C1 = {0.f, 0.f, 0.f, 0.f};
    C1 = __builtin_amdgcn_mfma_f32_16x16x32_f16(af10, b0, C1, 0, 0, 0);
    C1 = __builtin_amdgcn_mfma_f32_16x16x32_f16(af11, b1, C1, 0, 0, 0);
    const int i = (jt - 24) * 2 + (c >> 3);
#pragma unroll
    for (int r = 0; r < 4; r++) {
      t3[0][r] += s_sn[w][quad * 4 + r][i] * (C0[r] + bias);
      t3[1][r] += s_sn[w][16 + quad * 4 + r][i] * (C1[r] + bias);
    }
  }
#pragma unroll 2
  for (int jt = 32; jt < 36; jt++) {
    f16x8 b0 = *(const f16x8*)(wb + jt * 1024);
    f16x8 b1 = *(const f16x8*)(wb + jt * 1024 + 32);
    float bias = bp[jt * 16];
    f32x4 C0 = {0.f, 0.f, 0.f, 0.f};
    C0 = __builtin_amdgcn_mfma_f32_16x16x32_f16(af00, b0, C0, 0, 0, 0);
    C0 = __builtin_amdgcn_mfma_f32_16x16x32_f16(af01, b1, C0, 0, 0, 0);
    f32x4 C1 = {0.f, 0.f, 0.f, 0.f};
    C1 = __builtin_amdgcn_mfma_f32_16x16x32_f16(af10, b0, C1, 0, 0, 0);
    C1 = __builtin_amdgcn_mfma_f32_16x16x32_f16(af11, b1, C1, 0, 0, 0);
    const int i = (jt - 32) * 2 + (c >> 3);
#pragma unroll
    for (int r = 0; r < 4; r++) {
      float wv0 = C0[r] + bias;
      float wv1 = C1[r] + bias;
      mx[0][r] += s_v[w][quad * 4 + r][3 * i] * wv0;
      my[0][r] += s_v[w][quad * 4 + r][3 * i + 1] * wv0;
      mz[0][r] += s_v[w][quad * 4 + r][3 * i + 2] * wv0;
      mx[1][r] += s_v[w][16 + quad * 4 + r][3 * i] * wv1;
      my[1][r] += s_v[w][16 + quad * 4 + r][3 * i + 1] * wv1;
      mz[1][r] += s_v[w][16 + quad * 4 + r][3 * i + 2] * wv1;
    }
  }

  // fold the two column-halves (c and c^8 share output j = c&7)
#pragma unroll
  for (int g = 0; g < 2; g++)
#pragma unroll
    for (int r = 0; r < 4; r++) {
      t3[g][r] += __shfl_xor(t3[g][r], 8);
      mx[g][r] += __shfl_xor(mx[g][r], 8);
      my[g][r] += __shfl_xor(my[g][r], 8);
      mz[g][r] += __shfl_xor(mz[g][r], 8);
    }

  // ---- epilogue: run-compressed atomic scatter over sorted dst ----
#pragma unroll
  for (int g = 0; g < 2; g++) {
    const int e0g = g * 16 + quad * 4;
    int cur = __shfl(dstv, e0g);
    float acc0 = 0.f, a1x = 0.f, a1y = 0.f, a1z = 0.f, nacc = 0.f;
#pragma unroll
    for (int r = 0; r < 4; r++) {
      const int e = e0g + r;
      const int dst = __shfl(dstv, e);
      const float ew = __shfl(ewv, e);
      if (dst != cur) {
        atomicAdd(&agg0[(long long)cur * 16 + c], acc0);
        if (c < 8) {
          long long b = (long long)cur * 24 + (long long)c * 3;
          atomicAdd(&agg1[b], a1x);
          atomicAdd(&agg1[b + 1], a1y);
          atomicAdd(&agg1[b + 2], a1z);
        } else if (c == 8) {
          atomicAdd(&normb[cur], nacc);
        }
        acc0 = a1x = a1y = a1z = nacc = 0.f;
        cur = dst;
      }
      float sc = A_PATH * ew;
      float sh0 = s_sh[w][e][0];
      acc0 += (sh0 * p1[g][r] + p2[g][r]) * sc;
      if (c < 8) {
        float t3v = t3[g][r] * sc;
        float scs = sc * sh0;
        a1x += t3v * s_sh[w][e][1] + mx[g][r] * scs;
        a1y += t3v * s_sh[w][e][2] + my[g][r] * scs;
        a1z += t3v * s_sh[w][e][3] + mz[g][r] * scs;
      } else if (c == 8) {
        nacc += ew;
      }
    }
    atomicAdd(&agg0[(long long)cur * 16 + c], acc0);
    if (c < 8) {
      long long b = (long long)cur * 24 + (long long)c * 3;
      atomicAdd(&agg1[b], a1x);
      atomicAdd(&agg1[b + 1], a1y);
      atomicAdd(&agg1[b + 2], a1z);
    } else if (c == 8) {
      atomicAdd(&normb[cur], nacc);
    }
  }
}

// ---------------- final node kernel ----------------
extern "C" __global__ __launch_bounds__(64) void k_node(
    const float* __restrict__ x, const float* __restrict__ xnorm,
    const float* __restrict__ agg0, const float* __restrict__ agg1,
    const float* __restrict__ normb, const float* __restrict__ Wm_s,
    const float* __restrict__ Wm_v, const float* __restrict__ Wu_s,
    const float* __restrict__ Wu_v, const float* __restrict__ Ws_s,
    const float* __restrict__ Ws_v, const float* __restrict__ res_scale_p,
    float* __restrict__ out, int N) {
  __shared__ float sWms[384];
  __shared__ float sWmv[64];
  __shared__ float sWus[256];
  __shared__ float sWuv[64];
  __shared__ float sWss[256];
  __shared__ float sWsv[64];
  int t = threadIdx.x;
  for (int i = t; i < 384; i += 64) sWms[i] = Wm_s[i];
  sWmv[t] = Wm_v[t];
  for (int i = t; i < 256; i += 64) sWus[i] = Wu_s[i];
  sWuv[t] = Wu_v[t];
  for (int i = t; i < 256; i += 64) sWss[i] = Ws_s[i];
  sWsv[t] = Ws_v[t];
  __syncthreads();
  int n = blockIdx.x * 64 + t;
  if (n >= N) return;

  float inv = 1.0f / fmaxf(normb[n], EPSF);
  float4 a04[4], a14[6];
  {
    const float4* p = (const float4*)(agg0 + (long long)n * 16);
#pragma unroll
    for (int i = 0; i < 4; i++) a04[i] = p[i];
    const float4* q = (const float4*)(agg1 + (long long)n * 24);
#pragma unroll
    for (int i = 0; i < 6; i++) a14[i] = q[i];
  }
  float* a0 = (float*)a04;
  float* a1 = (float*)a14;
#pragma unroll
  for (int i = 0; i < 16; i++) a0[i] *= inv;
#pragma unroll
  for (int i = 0; i < 24; i++) a1[i] *= inv;

  float scal[16], gate[8];
#pragma unroll
  for (int jj = 0; jj < 24; jj++) {
    float acc = 0.f;
#pragma unroll
    for (int i = 0; i < 16; i++) acc += a0[i] * sWms[i * 24 + jj];
    acc *= Q16;
    if (jj < 16) scal[jj] = acc * sigm(acc);
    else gate[jj - 16] = sigm(acc);
  }
  float vg[24];
#pragma unroll
  for (int j = 0; j < 8; j++) {
    float g = gate[j];
#pragma unroll
    for (int cc = 0; cc < 3; cc++) {
      float acc = 0.f;
#pragma unroll
      for (int i = 0; i < 8; i++) acc += a1[i * 3 + cc] * sWmv[i * 8 + j];
      vg[j * 3 + cc] = acc * Q8 * g;
    }
  }
  float4 xn4[10], xo4[10];
  {
    const float4* p = (const float4*)(xnorm + (long long)n * 40);
    const float4* q = (const float4*)(x + (long long)n * 40);
#pragma unroll
    for (int i = 0; i < 10; i++) { xn4[i] = p[i]; xo4[i] = q[i]; }
  }
  const float* xn = (const float*)xn4;
  const float* xo = (const float*)xo4;
  float rs = res_scale_p[0];

  float4 ob[10];
  float* ov = (float*)ob;
#pragma unroll
  for (int j = 0; j < 16; j++) {
    float acc = 0.f, acc2 = 0.f;
#pragma unroll
    for (int i = 0; i < 16; i++) {
      acc += scal[i] * sWus[i * 16 + j];
      acc2 += xn[i] * sWss[i * 16 + j];
    }
    ov[j] = xo[j] + rs * ((acc + acc2) * Q16);
  }
#pragma unroll
  for (int j = 0; j < 8; j++) {
#pragma unroll
    for (int cc = 0; cc < 3; cc++) {
      float acc = 0.f;
#pragma unroll
      for (int i = 0; i < 8; i++)
        acc += vg[i * 3 + cc] * sWuv[i * 8 + j] + xn[16 + i * 3 + cc] * sWsv[i * 8 + j];
      ov[16 + j * 3 + cc] = xo[16 + j * 3 + cc] + rs * (acc * Q8);
    }
  }
  float4* po = (float4*)(out + (long long)n * 40);
#pragma unroll
  for (int i = 0; i < 10; i++) po[i] = ob[i];
}

// ---------------- launch ----------------
extern "C" void kernel_launch(void* const* d_in, const int* in_sizes, int n_in,
                              void* d_out, int out_size, void* d_ws, size_t ws_size,
                              hipStream_t stream) {
  const float* x = (const float*)d_in[0];
  const int* esrc = (const int*)d_in[1];
  const int* edst = (const int*)d_in[2];
  const float* sh = (const float*)d_in[3];
  const float* rbf = (const float*)d_in[4];
  const float* elen = (const float*)d_in[5];
  const float* w_r1 = (const float*)d_in[6];
  const float* b_r1 = (const float*)d_in[7];
  const float* w_r2 = (const float*)d_in[8];
  const float* b_r2 = (const float*)d_in[9];
  const float* w_g1 = (const float*)d_in[10];
  const float* b_g1 = (const float*)d_in[11];
  const float* w_g2 = (const float*)d_in[12];
  const float* b_g2 = (const float*)d_in[13];
  const float* Wm_s = (const float*)d_in[14];
  const float* Wm_v = (const float*)d_in[15];
  const float* Wu_s = (const float*)d_in[16];
  const float* Wu_v = (const float*)d_in[17];
  const float* Ws_s = (const float*)d_in[18];
  const float* Ws_v = (const float*)d_in[19];
  const float* res_scale = (const float*)d_in[20];

  const int N = in_sizes[0] / 40;
  const int E = in_sizes[1];

  char* ws = (char*)d_ws;
  size_t off = 0;
  float* xnorm = (float*)(ws + off); off += (size_t)N * 40 * sizeof(float);
  off = (off + 255) & ~(size_t)255;
  float* agg0 = (float*)(ws + off); off += (size_t)N * 16 * sizeof(float);
  float* agg1 = (float*)(ws + off); off += (size_t)N * 24 * sizeof(float);
  float* normb = (float*)(ws + off); off += (size_t)N * sizeof(float);
  off = (off + 255) & ~(size_t)255;
  f16* W2T = (f16*)(ws + off); off += (size_t)WNUM * 64 * sizeof(f16);
  off = (off + 255) & ~(size_t)255;
  int* hist   = (int*)(ws + off); off += (size_t)N * sizeof(int);
  int* iscan  = (int*)(ws + off); off += (size_t)N * sizeof(int);
  int* cursor = (int*)(ws + off); off += (size_t)N * sizeof(int);
  int* bsum   = (int*)(ws + off); off += 256 * sizeof(int);
  off = (off + 255) & ~(size_t)255;
  int* perm   = (int*)(ws + off); off += (size_t)E * sizeof(int);

  hipMemsetAsync(agg0, 0, (size_t)N * 41 * sizeof(float), stream);
  hipMemsetAsync(hist, 0, (size_t)N * sizeof(int), stream);

  const int nbE = (E + 255) / 256;
  const int nbN = (N + 255) / 256;

  k_hist<<<nbE, 256, 0, stream>>>(edst, hist, E);
  k_scan1<<<nbN, 256, 0, stream>>>(hist, iscan, bsum, N);
  k_scan2<<<1, 256, 0, stream>>>(bsum, nbN);
  k_scan3<<<nbN, 256, 0, stream>>>(hist, iscan, bsum, cursor, N);
  k_scatter<<<nbE, 256, 0, stream>>>(edst, cursor, perm, E);

  k_prep_w2t<<<(HID * WNUM + 255) / 256, 256, 0, stream>>>(w_r2, W2T);
  k_xnorm<<<(N + 63) / 64, 64, 0, stream>>>(x, xnorm, N);

  int nblk = (E + 127) / 128;
  k_edge<<<nblk, 256, 0, stream>>>(xnorm, perm, esrc, edst, sh, rbf, elen,
                                   w_r1, b_r1, w_g1, b_g1, w_g2, b_g2, b_r2,
                                   W2T, agg0, agg1, normb, E);

  k_node<<<(N + 63) / 64, 64, 0, stream>>>(x, xnorm, agg0, agg1, normb, Wm_s,
                                           Wm_v, Wu_s, Wu_v, Ws_s, Ws_v,
                                           res_scale, (float*)d_out, N);
}